// Round 18
// baseline (304.642 us; speedup 1.0000x reference)
//
#include <hip/hip_runtime.h>

#define HOP 256
#define CUT 513
#define T_FRAMES 1021
#define N_SAMPLES 262144
#define BATCH 16
#define NWG 2048                  // 16 batches x 128 blocks; 2 waves/block
#define FLAG_T 0.01f              // |im| flag threshold (fp32 FFT err ~2e-4)

// 6-bit bit reversal
__device__ __forceinline__ int bitrev6(int v) {
    return ((v & 1) << 5) | ((v & 2) << 3) | ((v & 4) << 1)
         | ((v & 8) >> 1) | ((v & 16) >> 3) | ((v & 32) >> 5);
}
// LDS slot for (k, tt in 0..7): stride 9 + XOR swizzle [R17-verified]
__device__ __forceinline__ int slotOf(int k, int tt) {
    return 9 * k + (tt ^ ((k >> 4) & 7));
}
// W_1024^k as (cos,sin), arg in revolutions [R7-verified]
__device__ __forceinline__ float2 twid(float rev) {
    return make_float2(__builtin_amdgcn_cosf(rev), __builtin_amdgcn_sinf(rev));
}
__device__ __forceinline__ float2 cmulwf(float yr, float yi, float2 w) {
    return make_float2(yr * w.x + yi * w.y, yi * w.x - yr * w.y);
}
// fast atan2 [R13-verified]
__device__ __forceinline__ float fast_atan2f(float y, float x) {
    const float PI  = 3.14159265358979323846f;
    const float PI2 = 1.57079632679489661923f;
    float ay = __builtin_fabsf(y), ax = __builtin_fabsf(x);
    float mx = fmaxf(ax, ay), mn = fminf(ax, ay);
    float r  = mn * __builtin_amdgcn_rcpf(mx);
    float s  = r * r;
    float p  = r * (0.99997726f + s * (-0.33262347f + s * (0.19354346f
             + s * (-0.11643287f + s * (0.05265332f + s * (-0.01172120f))))));
    p = (ay > ax) ? (PI2 - p) : p;
    p = (x < 0.0f) ? (PI - p) : p;
    return __builtin_copysignf(p, y);
}
// fp64 (cos,sin) of 2*pi*e/1024 [R16-verified]
__device__ __forceinline__ double2 wexp64(int e) {
    const int d = e & 63, c = (e >> 6) & 3, a = (e >> 8) & 3;
    double xx = (6.2831853071795864769252867665590057684 / 1024.0) * (double)d;
    double x2 = xx * xx;
    double cc = 1.0 + x2 * (-0.5 + x2 * (1.0/24.0 + x2 * (-1.0/720.0
               + x2 * (1.0/40320.0 + x2 * (-1.0/3628800.0)))));
    double ss = xx * (1.0 + x2 * (-1.0/6.0 + x2 * (1.0/120.0 + x2 * (-1.0/5040.0
               + x2 * (1.0/362880.0 + x2 * (-1.0/39916800.0))))));
    double kc = (c == 0) ? 1.0
              : (c == 1) ? 0.92387953251128675612818318939679
              : (c == 2) ? 0.70710678118654752440084436210485
                         : 0.38268343236508977172845998403040;
    double ks = (c == 0) ? 0.0
              : (c == 1) ? 0.38268343236508977172845998403040
              : (c == 2) ? 0.70710678118654752440084436210485
                         : 0.92387953251128675612818318939679;
    double cr = cc * kc - ss * ks;
    double ci = ss * kc + cc * ks;
    double2 r;
    r.x = (a == 0) ? cr : ((a == 1) ? -ci : ((a == 2) ? -cr : ci));
    r.y = (a == 0) ? ci : ((a == 1) ?  cr : ((a == 2) ? -ci : -cr));
    return r;
}

__global__ __launch_bounds__(128, 3) void stft_fft_kernel(
    const float* __restrict__ x,
    const float* __restrict__ basis,
    float* __restrict__ out)
{
    __shared__ float sbuf[4640];          // slotOf-addressed [k][tt<8], 18.5KB

    const int tid  = threadIdx.x;
    const int lane = tid & 63;
    const int wv   = tid >> 6;            // 0..1

    // XCD-chunked bijective swizzle (2048 % 8 == 0)
    const int sbw = (blockIdx.x & 7) * (NWG / 8) + (blockIdx.x >> 3);
    const int b   = sbw >> 7;             // batch (128 blocks per batch)
    const int blk = sbw & 127;
    const int tb  = blk * 8;              // block's t-base (8 frames)
    const int t0  = tb + 4 * wv;          // wave's 4 frames t0..t0+3
    const bool v1 = (t0 + 1) < T_FRAMES;
    const bool v2 = (t0 + 2) < T_FRAMES;
    const bool v3 = (t0 + 3) < T_FRAMES;

    const float* xptr  = x + (size_t)b * N_SAMPLES + (size_t)t0 * HOP;
    const float* wrow  = basis;
    const float* nyrow = basis + 1025 * 1024;

    // ---- load 1792-sample span (28 regs); clamp only for the tail wave
    float xv[28];
    if (t0 <= 1017) {
        #pragma unroll
        for (int j = 0; j < 28; ++j) xv[j] = xptr[64 * j + lane];
    } else {
        const int s0 = t0 * HOP;
        #pragma unroll
        for (int j = 0; j < 28; ++j) {
            int off = 64 * j + lane;
            xv[j] = (s0 + off < N_SAMPLES) ? xptr[off] : 0.0f;
        }
    }

    // ---- pack 2 packed FFTs (frames A,B | C,D); fp64 DC/NyRe, fp32 NyIm
    float2 z1[16], z2[16];
    float IA = 0.f, IB = 0.f, IC = 0.f, ID = 0.f;
    double dA = 0.0, dB = 0.0, dC = 0.0, dD = 0.0;
    #pragma unroll
    for (int r = 0; r < 16; ++r) {
        int n = 64 * r + lane;
        float wn = wrow[n], cn = nyrow[n];
        float a = xv[r], bb = xv[r + 4], c = xv[r + 8], d = xv[r + 12];
        z1[r] = make_float2(wn * a, wn * bb);
        z2[r] = make_float2(wn * c, wn * d);
        IA += cn * a;  IB += cn * bb;  IC += cn * c;  ID += cn * d;
        dA += (double)wn * (double)a;  dB += (double)wn * (double)bb;
        dC += (double)wn * (double)c;  dD += (double)wn * (double)d;
    }
    double nA = (lane & 1) ? -dA : dA;    // Nyquist re partials: (-1)^lane
    double nB = (lane & 1) ? -dB : dB;
    double nC = (lane & 1) ? -dC : dC;
    double nD = (lane & 1) ? -dD : dD;
    #pragma unroll
    for (int off = 32; off > 0; off >>= 1) {
        IA += __shfl_xor(IA, off); IB += __shfl_xor(IB, off);
        IC += __shfl_xor(IC, off); ID += __shfl_xor(ID, off);
        dA += __shfl_xor(dA, off); dB += __shfl_xor(dB, off);
        dC += __shfl_xor(dC, off); dD += __shfl_xor(dD, off);
        nA += __shfl_xor(nA, off); nB += __shfl_xor(nB, off);
        nC += __shfl_xor(nC, off); nD += __shfl_xor(nD, off);
    }

    // ---- stage 0: radix-4 DIF stride 256, shared twiddles [R7-verified]
    #pragma unroll
    for (int r0 = 0; r0 < 4; ++r0) {
        float nf = (float)(64 * r0 + lane);
        float2 w1 = twid(nf * (1.0f / 1024.0f));
        float2 w2 = twid(nf * (2.0f / 1024.0f));
        float2 w3 = twid(nf * (3.0f / 1024.0f));
        {
            float2 A = z1[r0], B = z1[r0+4], C = z1[r0+8], D = z1[r0+12];
            float t0r = A.x+C.x, t0i = A.y+C.y, t1r = A.x-C.x, t1i = A.y-C.y;
            float t2r = B.x+D.x, t2i = B.y+D.y, t3r = B.x-D.x, t3i = B.y-D.y;
            z1[r0]      = make_float2(t0r+t2r, t0i+t2i);
            z1[r0 + 4]  = cmulwf(t1r+t3i, t1i-t3r, w1);
            z1[r0 + 8]  = cmulwf(t0r-t2r, t0i-t2i, w2);
            z1[r0 + 12] = cmulwf(t1r-t3i, t1i+t3r, w3);
        }
        {
            float2 A = z2[r0], B = z2[r0+4], C = z2[r0+8], D = z2[r0+12];
            float t0r = A.x+C.x, t0i = A.y+C.y, t1r = A.x-C.x, t1i = A.y-C.y;
            float t2r = B.x+D.x, t2i = B.y+D.y, t3r = B.x-D.x, t3i = B.y-D.y;
            z2[r0]      = make_float2(t0r+t2r, t0i+t2i);
            z2[r0 + 4]  = cmulwf(t1r+t3i, t1i-t3r, w1);
            z2[r0 + 8]  = cmulwf(t0r-t2r, t0i-t2i, w2);
            z2[r0 + 12] = cmulwf(t1r-t3i, t1i+t3r, w3);
        }
    }

    // ---- stage 1: radix-4 DIF stride 64, shared twiddles [R7-verified]
    {
        float fl = (float)lane;
        float2 w1 = twid(fl * (4.0f / 1024.0f));
        float2 w2 = twid(fl * (8.0f / 1024.0f));
        float2 w3 = twid(fl * (12.0f / 1024.0f));
        #pragma unroll
        for (int g = 0; g < 4; ++g) {
            {
                float2 A = z1[4*g], B = z1[4*g+1], C = z1[4*g+2], D = z1[4*g+3];
                float t0r = A.x+C.x, t0i = A.y+C.y, t1r = A.x-C.x, t1i = A.y-C.y;
                float t2r = B.x+D.x, t2i = B.y+D.y, t3r = B.x-D.x, t3i = B.y-D.y;
                z1[4*g]     = make_float2(t0r+t2r, t0i+t2i);
                z1[4*g + 1] = cmulwf(t1r+t3i, t1i-t3r, w1);
                z1[4*g + 2] = cmulwf(t0r-t2r, t0i-t2i, w2);
                z1[4*g + 3] = cmulwf(t1r-t3i, t1i+t3r, w3);
            }
            {
                float2 A = z2[4*g], B = z2[4*g+1], C = z2[4*g+2], D = z2[4*g+3];
                float t0r = A.x+C.x, t0i = A.y+C.y, t1r = A.x-C.x, t1i = A.y-C.y;
                float t2r = B.x+D.x, t2i = B.y+D.y, t3r = B.x-D.x, t3i = B.y-D.y;
                z2[4*g]     = make_float2(t0r+t2r, t0i+t2i);
                z2[4*g + 1] = cmulwf(t1r+t3i, t1i-t3r, w1);
                z2[4*g + 2] = cmulwf(t0r-t2r, t0i-t2i, w2);
                z2[4*g + 3] = cmulwf(t1r-t3i, t1i+t3r, w3);
            }
        }
    }

    // ---- stages 2..7: radix-2 across lanes, branchless, 2-FFT interleaved
    #pragma unroll
    for (int st = 0; st < 6; ++st) {
        const int h = 32 >> st;
        const bool hi = (lane & h) != 0;
        float2 t = twid((float)(lane & (h-1)) * ((float)(512/h) * (1.0f/1024.0f)));
        float wx = hi ? t.x : 1.0f;
        float wy = hi ? t.y : 0.0f;
        const float sgnD = hi ? -1.0f : 1.0f;
        #pragma unroll
        for (int r = 0; r < 16; ++r) {
            float vr = __shfl_xor(z1[r].x, h);
            float vi = __shfl_xor(z1[r].y, h);
            float sr = sgnD * z1[r].x + vr;
            float si = sgnD * z1[r].y + vi;
            z1[r] = make_float2(sr * wx + si * wy, si * wx - sr * wy);
            float vr2 = __shfl_xor(z2[r].x, h);
            float vi2 = __shfl_xor(z2[r].y, h);
            float sr2 = sgnD * z2[r].x + vr2;
            float si2 = sgnD * z2[r].y + vi2;
            z2[r] = make_float2(sr2 * wx + si2 * wy, si2 * wx - sr2 * wy);
        }
    }

    // ---- epilogue: unpack into statically-indexed held (rf,if) per FFT
    const int laneE = lane & ~1;
    const int RlE = bitrev6(laneE);
    const int lpA = bitrev6(63 - RlE);
    const int lpB = bitrev6((64 - RlE) & 63);
    const int SIG[16] = {0, 3, 2, 1, 15, 14, 13, 12, 11, 10, 9, 8, 7, 6, 5, 4};
    const bool isA = !(lane & 1);
    const bool okW1 = isA ? true : v1;
    const bool okW2 = isA ? v2 : v3;

    float rf1[16], if1[16], rf2[16], if2[16];
    unsigned fl1 = 0, fl2 = 0;
    #pragma unroll
    for (int r = 0; r < 16; ++r) {
        const int lp = (r == 0) ? lpB : lpA;
        float ax = __shfl(z1[r].x, laneE);
        float ay = __shfl(z1[r].y, laneE);
        float px = __shfl(z1[SIG[r]].x, lp);
        float py = __shfl(z1[SIG[r]].y, lp);
        rf1[r] = 0.5f * (isA ? (ax + px) : (ay + py));
        if1[r] = 0.5f * (isA ? (ay - py) : (px - ax));
        float ax2 = __shfl(z2[r].x, laneE);
        float ay2 = __shfl(z2[r].y, laneE);
        float px2 = __shfl(z2[SIG[r]].x, lp);
        float py2 = __shfl(z2[SIG[r]].y, lp);
        rf2[r] = 0.5f * (isA ? (ax2 + px2) : (ay2 + py2));
        if2[r] = 0.5f * (isA ? (ay2 - py2) : (px2 - ax2));
        const int rho = ((r & 3) << 2) | (r >> 2);
        const int k = 16 * RlE + rho;
        if (okW1 && __builtin_fabsf(if1[r]) < FLAG_T && k != 0) fl1 |= (1u << r);
        if (okW2 && __builtin_fabsf(if2[r]) < FLAG_T && k != 0) fl2 |= (1u << r);
    }

    // ---- repair: static-r outer (no dynamic reg indexing), exact fp64 dots
    #pragma unroll
    for (int r = 0; r < 16; ++r) {
        const int rho = ((r & 3) << 2) | (r >> 2);
        #pragma unroll
        for (int ff = 0; ff < 2; ++ff) {
            unsigned long long m = __ballot(((ff == 0 ? fl1 : fl2) >> r) & 1);
            while (m) {
                int L = __ffsll(m) - 1;
                m &= m - 1;
                int k = 16 * bitrev6(L & ~1) + rho;
                const float* px = xptr + (2 * ff + (L & 1)) * HOP;
                double2 cur = wexp64((k * lane) & 1023);
                double2 S   = wexp64((k * 64) & 1023);
                double re = 0.0, im = 0.0;
                #pragma unroll
                for (int j = 0; j < 16; ++j) {
                    int n = 64 * j + lane;
                    double xw = (double)wrow[n] * (double)px[n];
                    re += xw * cur.x;
                    im -= xw * cur.y;
                    double nx = cur.x * S.x - cur.y * S.y;
                    double ny = cur.y * S.x + cur.x * S.y;
                    cur.x = nx; cur.y = ny;
                }
                #pragma unroll
                for (int off = 32; off > 0; off >>= 1) {
                    re += __shfl_xor(re, off);
                    im += __shfl_xor(im, off);
                }
                if (lane == L) {
                    if (ff == 0) { rf1[r] = (float)re; if1[r] = (float)im; }
                    else         { rf2[r] = (float)re; if2[r] = (float)im; }
                }
            }
        }
    }

    const int tt1 = 4 * wv + (lane & 1);
    const int tt2 = 4 * wv + 2 + (lane & 1);
    float* omag = out + (size_t)b * CUT * T_FRAMES;
    float* oph  = omag + (size_t)BATCH * CUT * T_FRAMES;

    // ======== pass 1: magnitude ========
    #pragma unroll
    for (int r = 0; r < 16; ++r) {
        const int rho = ((r & 3) << 2) | (r >> 2);
        const int k = 16 * RlE + rho;
        sbuf[slotOf(k, tt1)] = sqrtf(rf1[r]*rf1[r] + if1[r]*if1[r]);
        sbuf[slotOf(k, tt2)] = sqrtf(rf2[r]*rf2[r] + if2[r]*if2[r]);
    }
    if (lane == 0) {   // DC overwrite (fp64): |re|, im exactly +0
        sbuf[slotOf(0, 4*wv + 0)] = __builtin_fabsf((float)dA);
        sbuf[slotOf(0, 4*wv + 1)] = __builtin_fabsf((float)dB);
        sbuf[slotOf(0, 4*wv + 2)] = __builtin_fabsf((float)dC);
        sbuf[slotOf(0, 4*wv + 3)] = __builtin_fabsf((float)dD);
    }
    if (lane == 1) {   // Nyquist: re fp64 alt-sum, im exact dots
        float a0 = (float)nA, a1 = (float)nB, a2 = (float)nC, a3 = (float)nD;
        sbuf[slotOf(512, 4*wv + 0)] = sqrtf(a0*a0 + IA*IA);
        sbuf[slotOf(512, 4*wv + 1)] = sqrtf(a1*a1 + IB*IB);
        sbuf[slotOf(512, 4*wv + 2)] = sqrtf(a2*a2 + IC*IC);
        sbuf[slotOf(512, 4*wv + 3)] = sqrtf(a3*a3 + ID*ID);
    }
    __syncthreads();
    for (int f = tid; f < CUT * 8; f += 128) {
        int k = f >> 3, tt = f & 7, t = tb + tt;
        if (t < T_FRAMES) omag[(size_t)k * T_FRAMES + t] = sbuf[slotOf(k, tt)];
    }
    __syncthreads();

    // ======== pass 2: phase ========
    #pragma unroll
    for (int r = 0; r < 16; ++r) {
        const int rho = ((r & 3) << 2) | (r >> 2);
        const int k = 16 * RlE + rho;
        sbuf[slotOf(k, tt1)] = fast_atan2f(if1[r], rf1[r]);
        sbuf[slotOf(k, tt2)] = fast_atan2f(if2[r], rf2[r]);
    }
    if (lane == 0) {
        sbuf[slotOf(0, 4*wv + 0)] = fast_atan2f(0.0f, (float)dA);
        sbuf[slotOf(0, 4*wv + 1)] = fast_atan2f(0.0f, (float)dB);
        sbuf[slotOf(0, 4*wv + 2)] = fast_atan2f(0.0f, (float)dC);
        sbuf[slotOf(0, 4*wv + 3)] = fast_atan2f(0.0f, (float)dD);
    }
    if (lane == 1) {
        sbuf[slotOf(512, 4*wv + 0)] = fast_atan2f(IA, (float)nA);
        sbuf[slotOf(512, 4*wv + 1)] = fast_atan2f(IB, (float)nB);
        sbuf[slotOf(512, 4*wv + 2)] = fast_atan2f(IC, (float)nC);
        sbuf[slotOf(512, 4*wv + 3)] = fast_atan2f(ID, (float)nD);
    }
    __syncthreads();
    for (int f = tid; f < CUT * 8; f += 128) {
        int k = f >> 3, tt = f & 7, t = tb + tt;
        if (t < T_FRAMES) oph[(size_t)k * T_FRAMES + t] = sbuf[slotOf(k, tt)];
    }
}

extern "C" void kernel_launch(void* const* d_in, const int* in_sizes, int n_in,
                              void* d_out, int out_size, void* d_ws, size_t ws_size,
                              hipStream_t stream) {
    (void)in_sizes; (void)n_in; (void)d_ws; (void)ws_size; (void)out_size;
    const float* x     = (const float*)d_in[0];
    const float* basis = (const float*)d_in[1];
    float* out = (float*)d_out;
    dim3 grid(NWG);     // 2048 blocks x 2 waves, 4 frames per wave
    dim3 block(128);
    stft_fft_kernel<<<grid, block, 0, stream>>>(x, basis, out);
}

// Round 19
// 54.834 us; speedup vs baseline: 5.5557x; 5.5557x over previous
//
#include <hip/hip_runtime.h>

#define HOP 256
#define CUT 513
#define T_FRAMES 1021
#define N_SAMPLES 262144
#define BATCH 16
#define NPAIR 511                 // frame pairs per batch (last pair is lone)
#define NWG 2044                  // 8176 wave-tasks / 4 waves per block
#define FLAG_T 0.01f              // |im| flag threshold (fp32 FFT err ~2e-4)

// 6-bit bit reversal
__device__ __forceinline__ int bitrev6(int v) {
    return ((v & 1) << 5) | ((v & 2) << 3) | ((v & 4) << 1)
         | ((v & 8) >> 1) | ((v & 16) >> 3) | ((v & 32) >> 5);
}
// LDS slot for (k, tt in 0..7): stride 9 + XOR swizzle [R17-verified]
__device__ __forceinline__ int slotOf(int k, int tt) {
    return 9 * k + (tt ^ ((k >> 4) & 7));
}
// W_1024^k as (cos,sin), arg in revolutions [R7-verified]
__device__ __forceinline__ float2 twid(float rev) {
    return make_float2(__builtin_amdgcn_cosf(rev), __builtin_amdgcn_sinf(rev));
}
__device__ __forceinline__ float2 cmulwf(float yr, float yi, float2 w) {
    return make_float2(yr * w.x + yi * w.y, yi * w.x - yr * w.y);
}
// fast atan2 [R13-verified]
__device__ __forceinline__ float fast_atan2f(float y, float x) {
    const float PI  = 3.14159265358979323846f;
    const float PI2 = 1.57079632679489661923f;
    float ay = __builtin_fabsf(y), ax = __builtin_fabsf(x);
    float mx = fmaxf(ax, ay), mn = fminf(ax, ay);
    float r  = mn * __builtin_amdgcn_rcpf(mx);
    float s  = r * r;
    float p  = r * (0.99997726f + s * (-0.33262347f + s * (0.19354346f
             + s * (-0.11643287f + s * (0.05265332f + s * (-0.01172120f))))));
    p = (ay > ax) ? (PI2 - p) : p;
    p = (x < 0.0f) ? (PI - p) : p;
    return __builtin_copysignf(p, y);
}
// fp64 (cos,sin) of 2*pi*e/1024 [R16-verified]
__device__ __forceinline__ double2 wexp64(int e) {
    const int d = e & 63, c = (e >> 6) & 3, a = (e >> 8) & 3;
    double xx = (6.2831853071795864769252867665590057684 / 1024.0) * (double)d;
    double x2 = xx * xx;
    double cc = 1.0 + x2 * (-0.5 + x2 * (1.0/24.0 + x2 * (-1.0/720.0
               + x2 * (1.0/40320.0 + x2 * (-1.0/3628800.0)))));
    double ss = xx * (1.0 + x2 * (-1.0/6.0 + x2 * (1.0/120.0 + x2 * (-1.0/5040.0
               + x2 * (1.0/362880.0 + x2 * (-1.0/39916800.0))))));
    double kc = (c == 0) ? 1.0
              : (c == 1) ? 0.92387953251128675612818318939679
              : (c == 2) ? 0.70710678118654752440084436210485
                         : 0.38268343236508977172845998403040;
    double ks = (c == 0) ? 0.0
              : (c == 1) ? 0.38268343236508977172845998403040
              : (c == 2) ? 0.70710678118654752440084436210485
                         : 0.92387953251128675612818318939679;
    double cr = cc * kc - ss * ks;
    double ci = ss * kc + cc * ks;
    double2 r;
    r.x = (a == 0) ? cr : ((a == 1) ? -ci : ((a == 2) ? -cr : ci));
    r.y = (a == 0) ? ci : ((a == 1) ?  cr : ((a == 2) ? -ci : -cr));
    return r;
}

__global__ __launch_bounds__(256, 4) void stft_fft_kernel(
    const float* __restrict__ x,
    const float* __restrict__ basis,
    float* __restrict__ out)
{
    __shared__ float smag[9 * CUT + 8];   // slotOf-addressed [k][tt]
    __shared__ float sph[9 * CUT + 8];

    const int tid  = threadIdx.x;
    const int lane = tid & 63;
    const int wv   = tid >> 6;

    // bijective XCD-chunked swizzle (NWG % 8 == 4); 4 consecutive pairs/block
    const int q8 = NWG >> 3, rem = NWG & 7;
    const int xcd = blockIdx.x & 7, idx = blockIdx.x >> 3;
    const int sb = (xcd < rem) ? (xcd * (q8 + 1) + idx)
                               : (rem * (q8 + 1) + (xcd - rem) * q8 + idx);
    const int task = sb * 4 + wv;
    const int b  = task / NPAIR;
    const int pr = task - b * NPAIR;
    const int t0 = 2 * pr;
    const bool has_b = (t0 + 1 < T_FRAMES);
    const int ttA = 2 * wv;               // this wave's LDS columns

    const float* xptr = x + (size_t)b * N_SAMPLES + (size_t)t0 * HOP;
    const float* wrow = basis;                          // row 0 == Hann window

    // ---- split-load packing: rolling 12-reg sample window (reg-pressure cut)
    float2 z[16];
    float IA = 0.f, IB = 0.f;
    double pA = 0.0, pB = 0.0;            // per-lane fp64 partial of sum(w*x)
    float xv[12];
    #pragma unroll
    for (int j = 0; j < 12; ++j) xv[j] = xptr[64 * j + lane];
    #pragma unroll
    for (int r = 0; r < 8; ++r) {         // uses j=r and j=r+4 (<=11)
        int n = 64 * r + lane;
        float wn = wrow[n];
        float cn = basis[1025 * 1024 + n];
        float xa = xv[r], xb2 = xv[r + 4];
        z[r] = make_float2(wn * xa, wn * xb2);
        IA += cn * xa;  IB += cn * xb2;
        pA += (double)wn * (double)xa;  pB += (double)wn * (double)xb2;
    }
    #pragma unroll
    for (int j = 0; j < 4; ++j) xv[j] = xptr[64 * (12 + j) + lane];   // j=12..15
    #pragma unroll
    for (int r = 8; r < 12; ++r) {        // A: j=r (slots 8..11); B: j=r+4 (slots 0..3)
        int n = 64 * r + lane;
        float wn = wrow[n];
        float cn = basis[1025 * 1024 + n];
        float xa = xv[r], xb2 = xv[r - 8];
        z[r] = make_float2(wn * xa, wn * xb2);
        IA += cn * xa;  IB += cn * xb2;
        pA += (double)wn * (double)xa;  pB += (double)wn * (double)xb2;
    }
    #pragma unroll
    for (int j = 4; j < 8; ++j)           // j=16..19, frame-B only
        xv[j] = has_b ? xptr[64 * (12 + j) + lane] : 0.0f;
    #pragma unroll
    for (int r = 12; r < 16; ++r) {       // A: j=r (slots 0..3); B: j=r+4 (slots 4..7)
        int n = 64 * r + lane;
        float wn = wrow[n];
        float cn = basis[1025 * 1024 + n];
        float xa = xv[r - 12], xb2 = xv[r - 8];
        z[r] = make_float2(wn * xa, wn * xb2);
        IA += cn * xa;  IB += cn * xb2;
        pA += (double)wn * (double)xa;  pB += (double)wn * (double)xb2;
    }

    // ---- shared-pair reduction: DC = pair-sum, NyRe = pair-difference
    double qA = __shfl_xor(pA, 1), qB = __shfl_xor(pB, 1);
    double dcA = pA + qA, dcB = pB + qB;
    double nrA = (lane & 1) ? (qA - pA) : (pA - qA);   // p_even - p_odd per pair
    double nrB = (lane & 1) ? (qB - pB) : (pB - qB);
    #pragma unroll
    for (int off = 2; off <= 32; off <<= 1) {
        dcA += __shfl_xor(dcA, off); dcB += __shfl_xor(dcB, off);
        nrA += __shfl_xor(nrA, off); nrB += __shfl_xor(nrB, off);
    }
    #pragma unroll
    for (int off = 32; off > 0; off >>= 1) {
        IA += __shfl_xor(IA, off); IB += __shfl_xor(IB, off);
    }

    // ---- stage 0: radix-4 DIF, stride 256 (in-lane) [R7-verified]
    #pragma unroll
    for (int r0 = 0; r0 < 4; ++r0) {
        float2 A = z[r0], B = z[r0 + 4], C = z[r0 + 8], D = z[r0 + 12];
        float t0r = A.x + C.x, t0i = A.y + C.y, t1r = A.x - C.x, t1i = A.y - C.y;
        float t2r = B.x + D.x, t2i = B.y + D.y, t3r = B.x - D.x, t3i = B.y - D.y;
        float nf = (float)(64 * r0 + lane);
        float2 w1 = twid(nf * (1.0f / 1024.0f));
        float2 w2 = twid(nf * (2.0f / 1024.0f));
        float2 w3 = twid(nf * (3.0f / 1024.0f));
        z[r0]      = make_float2(t0r + t2r, t0i + t2i);
        z[r0 + 4]  = cmulwf(t1r + t3i, t1i - t3r, w1);
        z[r0 + 8]  = cmulwf(t0r - t2r, t0i - t2i, w2);
        z[r0 + 12] = cmulwf(t1r - t3i, t1i + t3r, w3);
    }

    // ---- stage 1: radix-4 DIF, stride 64 (in-lane) [R7-verified]
    {
        float fl = (float)lane;
        float2 w1 = twid(fl * (4.0f / 1024.0f));
        float2 w2 = twid(fl * (8.0f / 1024.0f));
        float2 w3 = twid(fl * (12.0f / 1024.0f));
        #pragma unroll
        for (int g = 0; g < 4; ++g) {
            float2 A = z[4*g], B = z[4*g+1], C = z[4*g+2], D = z[4*g+3];
            float t0r = A.x + C.x, t0i = A.y + C.y, t1r = A.x - C.x, t1i = A.y - C.y;
            float t2r = B.x + D.x, t2i = B.y + D.y, t3r = B.x - D.x, t3i = B.y - D.y;
            z[4*g]     = make_float2(t0r + t2r, t0i + t2i);
            z[4*g + 1] = cmulwf(t1r + t3i, t1i - t3r, w1);
            z[4*g + 2] = cmulwf(t0r - t2r, t0i - t2i, w2);
            z[4*g + 3] = cmulwf(t1r - t3i, t1i + t3r, w3);
        }
    }

    // ---- stages 2..7: radix-2 DIF across lanes, branchless [R7+R11-verified]
    #pragma unroll
    for (int st = 0; st < 6; ++st) {
        const int h = 32 >> st;
        const bool hi = (lane & h) != 0;
        float2 t = twid((float)(lane & (h - 1)) * ((float)(512 / h) * (1.0f / 1024.0f)));
        float wx = hi ? t.x : 1.0f;
        float wy = hi ? t.y : 0.0f;
        const float sgnD = hi ? -1.0f : 1.0f;
        #pragma unroll
        for (int r = 0; r < 16; ++r) {
            float vr = __shfl_xor(z[r].x, h);
            float vi = __shfl_xor(z[r].y, h);
            float sr = sgnD * z[r].x + vr;
            float si = sgnD * z[r].y + vi;
            z[r] = make_float2(sr * wx + si * wy, si * wx - sr * wy);
        }
    }

    // position (r,lane) holds bin k = 16*bitrev6(lane) + drev4(r).
    // Lane-pair epilogue [R9-verified] -> LDS staging.
    const int laneE = lane & ~1;
    const int RlE = bitrev6(laneE);               // < 32
    const int lpA = bitrev6(63 - RlE);
    const int lpB = bitrev6((64 - RlE) & 63);
    const int SIG[16] = {0, 3, 2, 1, 15, 14, 13, 12, 11, 10, 9, 8, 7, 6, 5, 4};
    const bool isA = !(lane & 1);
    const bool okW = isA | has_b;
    const int myTT = ttA + (lane & 1);

    unsigned flags = 0;
    #pragma unroll
    for (int r = 0; r < 16; ++r) {
        const int lp = (r == 0) ? lpB : lpA;
        float ax = __shfl(z[r].x, laneE);
        float ay = __shfl(z[r].y, laneE);
        float px = __shfl(z[SIG[r]].x, lp);
        float py = __shfl(z[SIG[r]].y, lp);
        float rr = isA ? (ax + px) : (ay + py);
        float ii = isA ? (ay - py) : (px - ax);
        float rf  = 0.5f * rr;
        float iff = 0.5f * ii;
        const int rho = ((r & 3) << 2) | (r >> 2);
        const int k = 16 * RlE + rho;
        const int sl = slotOf(k, myTT);
        smag[sl] = sqrtf(rf * rf + iff * iff);
        sph[sl]  = fast_atan2f(iff, rf);
        if (okW && __builtin_fabsf(iff) < FLAG_T && k != 0) flags |= (1u << r);
    }

    // ---- bin 0 (DC): im exactly +0; re from fp64 sum
    if (lane == 0) {
        float rf = (float)dcA, rf2 = (float)dcB;
        int s0 = slotOf(0, ttA), s1 = slotOf(0, ttA + 1);
        smag[s0] = __builtin_fabsf(rf);
        sph[s0]  = fast_atan2f(0.0f, rf);
        smag[s1] = __builtin_fabsf(rf2);
        sph[s1]  = fast_atan2f(0.0f, rf2);
    }
    // ---- bin 512 (Nyquist): re fp64 pair-difference sum, im exact dots
    if (lane == 1) {
        float rf = (float)nrA, rf2 = (float)nrB;
        int s0 = slotOf(512, ttA), s1 = slotOf(512, ttA + 1);
        smag[s0] = sqrtf(rf * rf + IA * IA);
        sph[s0]  = fast_atan2f(IA, rf);
        smag[s1] = sqrtf(rf2 * rf2 + IB * IB);
        sph[s1]  = fast_atan2f(IB, rf2);
    }

    // ---- repair loop: wave-cooperative exact fp64 dot per flagged bin
    unsigned long long wm = __ballot(flags != 0);
    while (wm) {
        int L = __ffsll((unsigned long long)wm) - 1;
        wm &= wm - 1;
        unsigned flL = __shfl(flags, L);
        const int kb = 16 * bitrev6(L & ~1);
        const int f  = L & 1;
        const float* px = xptr + f * HOP;
        while (flL) {
            int r = __ffs(flL) - 1;
            flL &= flL - 1;
            int k = kb + (((r & 3) << 2) | (r >> 2));
            double2 cur = wexp64((k * lane) & 1023);
            double2 S   = wexp64((k * 64) & 1023);
            double re = 0.0, im = 0.0;
            #pragma unroll
            for (int j = 0; j < 16; ++j) {
                int n = 64 * j + lane;
                double xw = (double)wrow[n] * (double)px[n];
                re += xw * cur.x;
                im -= xw * cur.y;
                double nx = cur.x * S.x - cur.y * S.y;
                double ny = cur.y * S.x + cur.x * S.y;
                cur.x = nx; cur.y = ny;
            }
            #pragma unroll
            for (int off = 32; off > 0; off >>= 1) {
                re += __shfl_xor(re, off);
                im += __shfl_xor(im, off);
            }
            if (lane == L) {
                int sl = slotOf(k, ttA + f);
                smag[sl] = sqrtf((float)(re * re + im * im));
                sph[sl]  = fast_atan2f((float)im, (float)re);
            }
        }
    }

    __syncthreads();

    // ---- flush: coalesced 8-t-wide runs; per-column (b,t) recomputed
    const size_t PH = (size_t)BATCH * CUT * T_FRAMES;
    for (int f = tid; f < CUT * 8; f += 256) {
        int k = f >> 3, ttx = f & 7;
        int task_w = sb * 4 + (ttx >> 1);
        int bw  = task_w / NPAIR;
        int prw = task_w - bw * NPAIR;
        int tw  = 2 * prw + (ttx & 1);
        if (tw < T_FRAMES) {
            int sl = slotOf(k, ttx);
            size_t g = (size_t)bw * CUT * T_FRAMES + (size_t)k * T_FRAMES + tw;
            out[g]      = smag[sl];
            out[g + PH] = sph[sl];
        }
    }
}

extern "C" void kernel_launch(void* const* d_in, const int* in_sizes, int n_in,
                              void* d_out, int out_size, void* d_ws, size_t ws_size,
                              hipStream_t stream) {
    (void)in_sizes; (void)n_in; (void)d_ws; (void)ws_size; (void)out_size;
    const float* x     = (const float*)d_in[0];
    const float* basis = (const float*)d_in[1];
    float* out = (float*)d_out;
    dim3 grid(NWG);     // 2044 blocks x 4 waves
    dim3 block(256);
    stft_fft_kernel<<<grid, block, 0, stream>>>(x, basis, out);
}